// Round 6
// baseline (343.590 us; speedup 1.0000x reference)
//
#include <hip/hip_runtime.h>

#define SS 1024
#define BB 4096
#define HH 8
#define XSTRIDE (BB * HH)   // floats per timestep slice
#define NG 256              // groups of 4 steps

typedef float f32x2 __attribute__((ext_vector_type(2)));
typedef __attribute__((address_space(1))) const unsigned int guint;
typedef __attribute__((address_space(3))) unsigned int luint;

// DPP cross-lane (VALU pipe): xor1/xor2 via quad_perm, xor7 via row_half_mirror.
__device__ __forceinline__ int dpp_x1(int v) {
    return __builtin_amdgcn_mov_dpp(v, 0xB1, 0xF, 0xF, true);   // quad_perm [1,0,3,2]
}
__device__ __forceinline__ int dpp_x2(int v) {
    return __builtin_amdgcn_mov_dpp(v, 0x4E, 0xF, 0xF, true);   // quad_perm [2,3,0,1]
}
__device__ __forceinline__ int dpp_x7(int v) {
    return __builtin_amdgcn_mov_dpp(v, 0x141, 0xF, 0xF, true);  // row_half_mirror
}

// Butterfly register m holds h[j ^ MK[m]]; h-side weights pre-permuted to match.
__device__ __constant__ int MK_[8] = {0, 1, 2, 3, 7, 6, 5, 4};

// X-phase (chain C, step U): input-side pre-activations from the LDS tile.
// Weights/biases PRE-SCALED: r/z by -log2(e), n by +2*log2(e).
#define XSTEP(C, CI, U) do {                                                           \
    const float4 X0_ = xl[cur][CI][(U) * 16 + grp2];                                   \
    const float4 X1_ = xl[cur][CI][(U) * 16 + grp2 + 1];                               \
    f32x2 a0_ = {X0_.x, X0_.y}, a1_ = {X0_.z, X0_.w};                                  \
    f32x2 a2_ = {X1_.x, X1_.y}, a3_ = {X1_.z, X1_.w};                                  \
    f32x2 sr_ = {bias_r, 0.0f}, sz_ = {bias_z, 0.0f}, sn_ = {bni_s, 0.0f};             \
    sr_ = __builtin_elementwise_fma(a0_, wri[0], sr_);                                 \
    sz_ = __builtin_elementwise_fma(a0_, wzi[0], sz_);                                 \
    sn_ = __builtin_elementwise_fma(a0_, wni[0], sn_);                                 \
    sr_ = __builtin_elementwise_fma(a1_, wri[1], sr_);                                 \
    sz_ = __builtin_elementwise_fma(a1_, wzi[1], sz_);                                 \
    sn_ = __builtin_elementwise_fma(a1_, wni[1], sn_);                                 \
    sr_ = __builtin_elementwise_fma(a2_, wri[2], sr_);                                 \
    sz_ = __builtin_elementwise_fma(a2_, wzi[2], sz_);                                 \
    sn_ = __builtin_elementwise_fma(a2_, wni[2], sn_);                                 \
    sr_ = __builtin_elementwise_fma(a3_, wri[3], sr_);                                 \
    sz_ = __builtin_elementwise_fma(a3_, wzi[3], sz_);                                 \
    sn_ = __builtin_elementwise_fma(a3_, wni[3], sn_);                                 \
    C##xr[U] = sr_.x + sr_.y; C##xz[U] = sz_.x + sz_.y; C##xn[U] = sn_.x + sn_.y;      \
} while (0)

#define BFLY(C) do {                                                                   \
    const int hb_ = __float_as_int(C##h);                                              \
    const int t1_ = dpp_x1(hb_);                                                       \
    const int t2_ = dpp_x2(hb_);                                                       \
    const int t3_ = dpp_x2(t1_);                                                       \
    const int t4_ = dpp_x7(hb_);                                                       \
    const int t5_ = dpp_x7(t1_);                                                       \
    const int t6_ = dpp_x7(t2_);                                                       \
    const int t7_ = dpp_x7(t3_);                                                       \
    C##hv[0] = (f32x2){C##h, __int_as_float(t1_)};                                     \
    C##hv[1] = (f32x2){__int_as_float(t2_), __int_as_float(t3_)};                      \
    C##hv[2] = (f32x2){__int_as_float(t4_), __int_as_float(t5_)};                      \
    C##hv[3] = (f32x2){__int_as_float(t6_), __int_as_float(t7_)};                      \
} while (0)

// R-phase for BOTH chains, hand-interleaved: chain Q's independent ops fill
// chain P's dependent-chain (exp2/rcp) stalls.
#define RSTEP2(U, SIDX) do {                                                           \
    f32x2 Pr2 = {Pxr[U], 0.0f}, Qr2 = {Qxr[U], 0.0f};                                  \
    f32x2 Pz2 = {Pxz[U], 0.0f}, Qz2 = {Qxz[U], 0.0f};                                  \
    f32x2 Pn2 = {bnh_s, 0.0f},  Qn2 = {bnh_s, 0.0f};                                   \
    _Pragma("unroll")                                                                  \
    for (int p_ = 0; p_ < 4; ++p_) {                                                   \
        Pr2 = __builtin_elementwise_fma(Phv[p_], wrh[p_], Pr2);                        \
        Qr2 = __builtin_elementwise_fma(Qhv[p_], wrh[p_], Qr2);                        \
        Pz2 = __builtin_elementwise_fma(Phv[p_], wzh[p_], Pz2);                        \
        Qz2 = __builtin_elementwise_fma(Qhv[p_], wzh[p_], Qz2);                        \
        Pn2 = __builtin_elementwise_fma(Phv[p_], wnh[p_], Pn2);                        \
        Qn2 = __builtin_elementwise_fma(Qhv[p_], wnh[p_], Qn2);                        \
    }                                                                                  \
    const float PEr = __builtin_amdgcn_exp2f(Pr2.x + Pr2.y);                           \
    const float QEr = __builtin_amdgcn_exp2f(Qr2.x + Qr2.y);                           \
    const float PEz = __builtin_amdgcn_exp2f(Pz2.x + Pz2.y);                           \
    const float QEz = __builtin_amdgcn_exp2f(Qz2.x + Qz2.y);                           \
    const float Pr_ = __builtin_amdgcn_rcpf(1.0f + PEr);                               \
    const float Qr_ = __builtin_amdgcn_rcpf(1.0f + QEr);                               \
    const float Pz_ = __builtin_amdgcn_rcpf(1.0f + PEz);                               \
    const float Qz_ = __builtin_amdgcn_rcpf(1.0f + QEz);                               \
    const float PEn = __builtin_amdgcn_exp2f(fmaf(Pr_, Pn2.x + Pn2.y, Pxn[U]));        \
    const float QEn = __builtin_amdgcn_exp2f(fmaf(Qr_, Qn2.x + Qn2.y, Qxn[U]));        \
    const float Pn_ = fmaf(-2.0f, __builtin_amdgcn_rcpf(1.0f + PEn), 1.0f);            \
    const float Qn_ = fmaf(-2.0f, __builtin_amdgcn_rcpf(1.0f + QEn), 1.0f);            \
    Ph = Pn_ + Pz_ * (Ph - Pn_);                                                       \
    Qh = Qn_ + Qz_ * (Qh - Qn_);                                                       \
    BFLY(P);                                                                           \
    BFLY(Q);                                                                           \
    Pop[(size_t)(SIDX) * XSTRIDE] = Ph;                                                \
    Qop[(size_t)(SIDX) * XSTRIDE] = Qh;                                                \
} while (0)

// Stage a 4-step x-tile of one chain into LDS via DMA (zero VGPR cost).
// Lane L reads 16B at row (g*4 + L/16), bytes (L%16)*16 of the chain's 256B
// batch row; HW writes LDS base + L*16 -> linear 1KiB tile.
#define DMA_GROUP(CI, BGC, GRP, BUF) do {                                              \
    const float* gp_ = x + (size_t)((GRP) * 4 + (lane >> 4)) * XSTRIDE                 \
                         + (size_t)(BGC) * HH + (lane & 15) * 4;                       \
    __builtin_amdgcn_global_load_lds((guint*)gp_, (luint*)&xl[BUF][CI][0], 16, 0, 0);  \
} while (0)

// 8 lanes per batch element; TWO batch groups (chains P,Q) per wave.
__global__ __launch_bounds__(64, 1) void gru_kernel(
    const float* __restrict__ x,
    const float* __restrict__ w_ih,
    const float* __restrict__ w_hh,
    const float* __restrict__ b_ih,
    const float* __restrict__ b_hh,
    float* __restrict__ out)
{
    __shared__ float4 xl[2][2][64];   // [buf][chain][4 steps * 16 float4] = 4 KiB

    const int lane = threadIdx.x;
    const int j = lane & 7;
    const int grp2 = (lane >> 3) * 2;          // float4 index of this lane's batch row
    const int bgP = (blockIdx.x << 4) + (lane >> 3);
    const int bgQ = bgP + 8;
    const int bgP0 = blockIdx.x << 4;          // chain base batches (DMA source rows)
    const int bgQ0 = bgP0 + 8;

    const float SR = -1.4426950408889634f;     // -log2(e)
    const float SN = 2.8853900817779268f;      // 2*log2(e)

    f32x2 wri[4], wzi[4], wni[4];
    #pragma unroll
    for (int p = 0; p < 4; ++p) {
        wri[p] = (f32x2){SR * w_ih[j * 8 + 2 * p],        SR * w_ih[j * 8 + 2 * p + 1]};
        wzi[p] = (f32x2){SR * w_ih[(8 + j) * 8 + 2 * p],  SR * w_ih[(8 + j) * 8 + 2 * p + 1]};
        wni[p] = (f32x2){SN * w_ih[(16 + j) * 8 + 2 * p], SN * w_ih[(16 + j) * 8 + 2 * p + 1]};
    }
    f32x2 wrh[4], wzh[4], wnh[4];
    #pragma unroll
    for (int p = 0; p < 4; ++p) {
        const int c0 = j ^ MK_[2 * p], c1 = j ^ MK_[2 * p + 1];
        wrh[p] = (f32x2){SR * w_hh[j * 8 + c0],        SR * w_hh[j * 8 + c1]};
        wzh[p] = (f32x2){SR * w_hh[(8 + j) * 8 + c0],  SR * w_hh[(8 + j) * 8 + c1]};
        wnh[p] = (f32x2){SN * w_hh[(16 + j) * 8 + c0], SN * w_hh[(16 + j) * 8 + c1]};
    }
    const float bias_r = SR * (b_ih[j] + b_hh[j]);
    const float bias_z = SR * (b_ih[8 + j] + b_hh[8 + j]);
    const float bni_s  = SN * b_ih[16 + j];
    const float bnh_s  = SN * b_hh[16 + j];

    float* Pop = out + (size_t)bgP * HH + j;
    float* Qop = out + (size_t)bgQ * HH + j;
    float* Phl = out + (size_t)SS * BB * HH + (size_t)bgP * HH + j;
    float* Qhl = out + (size_t)SS * BB * HH + (size_t)bgQ * HH + j;

    float Ph = 0.0f, Qh = 0.0f;
    f32x2 Phv[4] = {{0,0},{0,0},{0,0},{0,0}};
    f32x2 Qhv[4] = {{0,0},{0,0},{0,0},{0,0}};
    float Pxr[4], Pxz[4], Pxn[4], Qxr[4], Qxz[4], Qxn[4];

    // prologue: DMA group 0 into buf 0
    DMA_GROUP(0, bgP0, 0, 0);
    DMA_GROUP(1, bgQ0, 0, 0);
    __builtin_amdgcn_sched_barrier(0);

    int cur = 0;
    for (int g = 0; g < NG; ++g) {
        // issue DMA for group g+1 into the other buffer (stays in flight
        // across this group's compute -- counted vmcnt, never drain to 0)
        const int gn = (g + 1 < NG) ? (g + 1) : (NG - 1);
        DMA_GROUP(0, bgP0, gn, cur ^ 1);
        DMA_GROUP(1, bgQ0, gn, cur ^ 1);
        __builtin_amdgcn_sched_barrier(0);
        if (g == 0) {
            // queue: [loads_g0(2), loads_g1(2)] -> need oldest 2 done
            asm volatile("s_waitcnt vmcnt(2)" ::: "memory");
        } else {
            // queue: [loads_g(2), stores_{g-1}(8), loads_{g+1}(2)] -> <=10
            // outstanding guarantees loads_g retired (in-order retirement)
            asm volatile("s_waitcnt vmcnt(10)" ::: "memory");
        }
        __builtin_amdgcn_sched_barrier(0);

        #pragma unroll
        for (int u = 0; u < 4; ++u) { XSTEP(P, 0, u); XSTEP(Q, 1, u); }
        #pragma unroll
        for (int u = 0; u < 4; ++u) RSTEP2(u, g * 4 + u);
        cur ^= 1;
    }
    *Phl = Ph;
    *Qhl = Qh;
}

extern "C" void kernel_launch(void* const* d_in, const int* in_sizes, int n_in,
                              void* d_out, int out_size, void* d_ws, size_t ws_size,
                              hipStream_t stream) {
    const float* x    = (const float*)d_in[0];
    const float* w_ih = (const float*)d_in[1];
    const float* w_hh = (const float*)d_in[2];
    const float* b_ih = (const float*)d_in[3];
    const float* b_hh = (const float*)d_in[4];
    float* out = (float*)d_out;
    gru_kernel<<<BB / 16, 64, 0, stream>>>(x, w_ih, w_hh, b_ih, b_hh, out);
}

// Round 7
// 134.766 us; speedup vs baseline: 2.5495x; 2.5495x over previous
//
#include <hip/hip_runtime.h>

#define SS 1024
#define BB 4096
#define HH 8
#define XSTRIDE (BB * HH)   // floats per timestep slice

typedef float f32x2 __attribute__((ext_vector_type(2)));

// DPP cross-lane (VALU pipe): xor1/xor2 via quad_perm, xor7 via row_half_mirror.
__device__ __forceinline__ int dpp_x1(int v) {
    return __builtin_amdgcn_mov_dpp(v, 0xB1, 0xF, 0xF, true);   // quad_perm [1,0,3,2]
}
__device__ __forceinline__ int dpp_x2(int v) {
    return __builtin_amdgcn_mov_dpp(v, 0x4E, 0xF, 0xF, true);   // quad_perm [2,3,0,1]
}
__device__ __forceinline__ int dpp_x7(int v) {
    return __builtin_amdgcn_mov_dpp(v, 0x141, 0xF, 0xF, true);  // row_half_mirror
}

// Butterfly register m holds h[j ^ MK[m]]; h-side weights pre-permuted to match.
__device__ __constant__ int MK_[8] = {0, 1, 2, 3, 7, 6, 5, 4};

// Pinned prefetch: inline-asm load cannot be sunk by the scheduler/RA (volatile,
// and the destination is live from here). This is the fix for rounds 2-6's
// collapsed prefetch (VGPR_Count 88..128 proved C-level loads always sank).
#define ALOAD(DST, PTR) asm volatile("global_load_dwordx4 %0, %1, off" : "=v"(DST) : "v"(PTR))

// Issue the 16 loads of one 8-step group (2 float4 per step).
#define LOADG(BUF, GRP) do {                                                           \
    const float* bp_ = xp + (size_t)(GRP) * 8 * XSTRIDE;                               \
    _Pragma("unroll")                                                                  \
    for (int u_ = 0; u_ < 8; ++u_) {                                                   \
        const float* p_ = bp_ + (size_t)u_ * XSTRIDE;                                  \
        ALOAD(BUF[2 * u_],     p_);                                                    \
        ALOAD(BUF[2 * u_ + 1], p_ + 4);                                                \
    }                                                                                  \
} while (0)

// Counted wait: retires only the oldest loads; in-flight stores/next loads stay
// outstanding (never drain to 0 -- round 6's store-retire stall lesson).
#define WAITV(N) do {                                                                  \
    asm volatile("s_waitcnt vmcnt(" #N ")" ::: "memory");                              \
    __builtin_amdgcn_sched_barrier(0);                                                 \
} while (0)

// X-phase for one step: input-side pre-activations. Weights/biases PRE-SCALED:
// r/z rows by -log2(e), n rows by +2*log2(e).
#define XFULL(BUF, V) do {                                                             \
    const float4 Xa_ = BUF[2 * (V)], Xb_ = BUF[2 * (V) + 1];                           \
    f32x2 a0_ = {Xa_.x, Xa_.y}, a1_ = {Xa_.z, Xa_.w};                                  \
    f32x2 a2_ = {Xb_.x, Xb_.y}, a3_ = {Xb_.z, Xb_.w};                                  \
    f32x2 sr_ = {bias_r, 0.0f}, sz_ = {bias_z, 0.0f}, sn_ = {bni_s, 0.0f};             \
    sr_ = __builtin_elementwise_fma(a0_, wri[0], sr_);                                 \
    sz_ = __builtin_elementwise_fma(a0_, wzi[0], sz_);                                 \
    sn_ = __builtin_elementwise_fma(a0_, wni[0], sn_);                                 \
    sr_ = __builtin_elementwise_fma(a1_, wri[1], sr_);                                 \
    sz_ = __builtin_elementwise_fma(a1_, wzi[1], sz_);                                 \
    sn_ = __builtin_elementwise_fma(a1_, wni[1], sn_);                                 \
    sr_ = __builtin_elementwise_fma(a2_, wri[2], sr_);                                 \
    sz_ = __builtin_elementwise_fma(a2_, wzi[2], sz_);                                 \
    sn_ = __builtin_elementwise_fma(a2_, wni[2], sn_);                                 \
    sr_ = __builtin_elementwise_fma(a3_, wri[3], sr_);                                 \
    sz_ = __builtin_elementwise_fma(a3_, wzi[3], sz_);                                 \
    sn_ = __builtin_elementwise_fma(a3_, wni[3], sn_);                                 \
    xr[(V)] = sr_.x + sr_.y; xz[(V)] = sz_.x + sz_.y; xn[(V)] = sn_.x + sn_.y;         \
} while (0)

// One 8-step group: R-steps with X-step (u+2) LEXICALLY WOVEN between the
// R-chain's dependent segments, so the in-order wave has issueable work during
// the exp2/rcp latency windows. (Rounds 3/4 kept phases separate -> no overlap.)
#define GROUP(BUF, SBASE) do {                                                         \
    XFULL(BUF, 0);                                                                     \
    XFULL(BUF, 1);                                                                     \
    _Pragma("unroll")                                                                  \
    for (int u = 0; u < 8; ++u) {                                                      \
        f32x2 hr2 = {xr[u], 0.0f}, hz2 = {xz[u], 0.0f}, hn2 = {bnh_s, 0.0f};           \
        _Pragma("unroll")                                                              \
        for (int p_ = 0; p_ < 4; ++p_) {                                               \
            hr2 = __builtin_elementwise_fma(hv2[p_], wrh[p_], hr2);                    \
            hz2 = __builtin_elementwise_fma(hv2[p_], wzh[p_], hz2);                    \
            hn2 = __builtin_elementwise_fma(hv2[p_], wnh[p_], hn2);                    \
        }                                                                              \
        const float srr = hr2.x + hr2.y;                                               \
        const float szz = hz2.x + hz2.y;                                               \
        const float snn = hn2.x + hn2.y;                                               \
        const bool W = (u + 2 < 8);                                                    \
        f32x2 sr_, sz_, sn_;                                                           \
        if (W) {   /* X(u+2) part 1: 6 pk_fma (fills dots->exp2 gap) */                \
            const float4 Xa_ = BUF[2 * (u + 2)];                                       \
            f32x2 a0_ = {Xa_.x, Xa_.y}, a1_ = {Xa_.z, Xa_.w};                          \
            sr_ = (f32x2){bias_r, 0.0f}; sz_ = (f32x2){bias_z, 0.0f};                  \
            sn_ = (f32x2){bni_s, 0.0f};                                                \
            sr_ = __builtin_elementwise_fma(a0_, wri[0], sr_);                         \
            sz_ = __builtin_elementwise_fma(a0_, wzi[0], sz_);                         \
            sn_ = __builtin_elementwise_fma(a0_, wni[0], sn_);                         \
            sr_ = __builtin_elementwise_fma(a1_, wri[1], sr_);                         \
            sz_ = __builtin_elementwise_fma(a1_, wzi[1], sz_);                         \
            sn_ = __builtin_elementwise_fma(a1_, wni[1], sn_);                         \
        }                                                                              \
        const float er = __builtin_amdgcn_exp2f(srr);                                  \
        const float ez = __builtin_amdgcn_exp2f(szz);                                  \
        if (W) {   /* X(u+2) part 2: 6 pk_fma (fills exp2 latency) */                  \
            const float4 Xb_ = BUF[2 * (u + 2) + 1];                                   \
            f32x2 a2_ = {Xb_.x, Xb_.y}, a3_ = {Xb_.z, Xb_.w};                          \
            sr_ = __builtin_elementwise_fma(a2_, wri[2], sr_);                         \
            sz_ = __builtin_elementwise_fma(a2_, wzi[2], sz_);                         \
            sn_ = __builtin_elementwise_fma(a2_, wni[2], sn_);                         \
            sr_ = __builtin_elementwise_fma(a3_, wri[3], sr_);                         \
            sz_ = __builtin_elementwise_fma(a3_, wzi[3], sz_);                         \
            sn_ = __builtin_elementwise_fma(a3_, wni[3], sn_);                         \
        }                                                                              \
        const float r_ = __builtin_amdgcn_rcpf(1.0f + er);                             \
        const float z_ = __builtin_amdgcn_rcpf(1.0f + ez);                             \
        if (W) {   /* X(u+2) reduce (fills rcp latency) */                             \
            xr[u + 2] = sr_.x + sr_.y;                                                 \
            xz[u + 2] = sz_.x + sz_.y;                                                 \
            xn[u + 2] = sn_.x + sn_.y;                                                 \
        }                                                                              \
        const float en = __builtin_amdgcn_exp2f(fmaf(r_, snn, xn[u]));                 \
        const float n_ = fmaf(-2.0f, __builtin_amdgcn_rcpf(1.0f + en), 1.0f);          \
        h = n_ + z_ * (h - n_);                                                        \
        const int hb_ = __float_as_int(h);                                             \
        const int t1_ = dpp_x1(hb_);                                                   \
        const int t2_ = dpp_x2(hb_);                                                   \
        const int t3_ = dpp_x2(t1_);                                                   \
        const int t4_ = dpp_x7(hb_);                                                   \
        const int t5_ = dpp_x7(t1_);                                                   \
        const int t6_ = dpp_x7(t2_);                                                   \
        const int t7_ = dpp_x7(t3_);                                                   \
        hv2[0] = (f32x2){h, __int_as_float(t1_)};                                      \
        hv2[1] = (f32x2){__int_as_float(t2_), __int_as_float(t3_)};                    \
        hv2[2] = (f32x2){__int_as_float(t4_), __int_as_float(t5_)};                    \
        hv2[3] = (f32x2){__int_as_float(t6_), __int_as_float(t7_)};                    \
        __builtin_nontemporal_store(h, &op[(size_t)((SBASE) + u) * XSTRIDE]);          \
    }                                                                                  \
} while (0)

// 8 lanes per batch element (lane j = hidden index), 8 batches per wave,
// 512 waves (2/CU). Weights in registers; x ping-pong buffers A/B pinned live
// via inline-asm loads.
__global__ __launch_bounds__(64, 1) void gru_kernel(
    const float* __restrict__ x,
    const float* __restrict__ w_ih,
    const float* __restrict__ w_hh,
    const float* __restrict__ b_ih,
    const float* __restrict__ b_hh,
    float* __restrict__ out)
{
    const int lane = threadIdx.x;
    const int j = lane & 7;
    const int bg = (blockIdx.x << 3) + (lane >> 3);

    const float SR = -1.4426950408889634f;     // -log2(e): sigmoid scale
    const float SN = 2.8853900817779268f;      // 2*log2(e): tanh scale

    f32x2 wri[4], wzi[4], wni[4];
    #pragma unroll
    for (int p = 0; p < 4; ++p) {
        wri[p] = (f32x2){SR * w_ih[j * 8 + 2 * p],        SR * w_ih[j * 8 + 2 * p + 1]};
        wzi[p] = (f32x2){SR * w_ih[(8 + j) * 8 + 2 * p],  SR * w_ih[(8 + j) * 8 + 2 * p + 1]};
        wni[p] = (f32x2){SN * w_ih[(16 + j) * 8 + 2 * p], SN * w_ih[(16 + j) * 8 + 2 * p + 1]};
    }
    f32x2 wrh[4], wzh[4], wnh[4];
    #pragma unroll
    for (int p = 0; p < 4; ++p) {
        const int c0 = j ^ MK_[2 * p], c1 = j ^ MK_[2 * p + 1];
        wrh[p] = (f32x2){SR * w_hh[j * 8 + c0],        SR * w_hh[j * 8 + c1]};
        wzh[p] = (f32x2){SR * w_hh[(8 + j) * 8 + c0],  SR * w_hh[(8 + j) * 8 + c1]};
        wnh[p] = (f32x2){SN * w_hh[(16 + j) * 8 + c0], SN * w_hh[(16 + j) * 8 + c1]};
    }
    const float bias_r = SR * (b_ih[j] + b_hh[j]);
    const float bias_z = SR * (b_ih[8 + j] + b_hh[8 + j]);
    const float bni_s  = SN * b_ih[16 + j];
    const float bnh_s  = SN * b_hh[16 + j];

    const float* xp = x + (size_t)bg * HH;
    float* op = out + (size_t)bg * HH + j;
    float* hlast = out + (size_t)SS * BB * HH + (size_t)bg * HH + j;

    float4 xA[16], xB[16];

    // prologue: groups 0 -> A, 1 -> B; wait only for A (16 = B's loads remain)
    LOADG(xA, 0);
    LOADG(xB, 1);
    WAITV(16);

    float h = 0.0f;
    f32x2 hv2[4] = {{0,0},{0,0},{0,0},{0,0}};
    float xr[8], xz[8], xn[8];

    // Steady state queue at each WAITV(24): [needed loads(16) | stores(8) +
    // next loads(16) stay in flight]. Prefetch distance = one full group.
    for (int g = 0; g < 128; g += 2) {
        GROUP(xA, g * 8);
        {
            const int ga = (g + 2 < 128) ? (g + 2) : 127;
            LOADG(xA, ga);
        }
        WAITV(24);
        GROUP(xB, (g + 1) * 8);
        {
            const int gb = (g + 3 < 128) ? (g + 3) : 127;
            LOADG(xB, gb);
        }
        WAITV(24);
    }
    *hlast = h;
}

extern "C" void kernel_launch(void* const* d_in, const int* in_sizes, int n_in,
                              void* d_out, int out_size, void* d_ws, size_t ws_size,
                              hipStream_t stream) {
    const float* x    = (const float*)d_in[0];
    const float* w_ih = (const float*)d_in[1];
    const float* w_hh = (const float*)d_in[2];
    const float* b_ih = (const float*)d_in[3];
    const float* b_hh = (const float*)d_in[4];
    float* out = (float*)d_out;
    gru_kernel<<<BB / 8, 64, 0, stream>>>(x, w_ih, w_hh, b_ih, b_hh, out);
}